// Round 1
// 223.537 us; speedup vs baseline: 1.0287x; 1.0287x over previous
//
#include <hip/hip_runtime.h>

// KNRM round 11: fp8(e4m3) embedding rows -> 5 lines/row instead of 10.
//  Model (locked R3-R9): main is MSHR/line-rate-bound (~27 G 64-B-lines/s
//  chip-wide); norm is streaming-BW bound; the two ~70us 480MB harness
//  poison fills are fixed. Only line cuts move anything -> halve the row.
//  fp8 e4m3 with PER-ROW dynamic scale (max|x| -> 64, dodges e4m3
//  subnormals at emb sigma~0.02); scale cancels in cosine because rnorm is
//  computed FROM the quantized values (exact-match cosine == 1 preserved,
//  needed by kernel0 sigma=1e-4). Row = 300 fp8 + 20 zero pad = 320 B.
//  Phase 0 (knrm_mark): flags[tok]=1 for all q/d tokens (~3 us).
//  Phase 1 (knrm_norm): fp32 -> scaled fp8 rows + rnorm from dequantized
//    values; referenced rows only.
//  Phase 2 (knrm_main8): same proven structure as R9/R10 main7 (8 waves x
//    4 steps of 16 d rows, register double-buffered B-frags under the exp
//    tail, one cross-lane reduce, fused epilogue) with
//    mfma_f32_16x16x32_fp8_fp8 (identical lane->(m,k) mapping as bf16
//    16x16x32: 8 elem/lane, k = quad*8+i).

#define B      256
#define BQ     32
#define BD     512
#define EDIM   300
#define ROWB   320   // bytes per fp8 row (300 data + 20 zero pad) = 5 lines
#define NK     11
#define QSTR   336   // q_buf row stride in BYTES: 16B-aligned, /4 == 84 = 20 mod 32

typedef float floatx4 __attribute__((ext_vector_type(4)));

__device__ __forceinline__ float sbc(float x) {   // force into SGPR
    return __uint_as_float(__builtin_amdgcn_readfirstlane(__float_as_uint(x)));
}

// ---------------- Phase 0: mark referenced vocab rows ----------------
__global__ __launch_bounds__(256)
void knrm_mark(const int* __restrict__ qtok, const int* __restrict__ dtok,
               unsigned char* __restrict__ flags)
{
    int i = blockIdx.x * 256 + threadIdx.x;
    const int NQ = B * BQ;              // 8192
    const int ND = B * BD;              // 131072
    if (i < NQ) flags[qtok[i]] = 1;
    else if (i < NQ + ND) flags[dtok[i - NQ]] = 1;
}

// ---------------- Phase 1: normalize / quantize referenced rows ----------------
// 8 lanes/row, 32 rows per 256-thread block.
// Pass A: load row into regs, reduce max|x| across the 8 lanes.
// Pass B: quantize (x * 64/max) to e4m3 (RNE via v_cvt_pk_fp8_f32), store
//         uint2 (8B) per lane per group (8 lanes x 8B = one 64B line),
//         accumulate ss from the DEQUANTIZED values -> rnorm.
__global__ __launch_bounds__(256)
void knrm_norm(const float* __restrict__ emb, const unsigned char* __restrict__ flags,
               unsigned char* __restrict__ ebf, float* __restrict__ rnorm, int V)
{
    int r    = blockIdx.x * 32 + (threadIdx.x >> 3);
    int part = threadIdx.x & 7;
    if (r >= V) return;
    if (!flags[r]) return;              // unreferenced: never read by main
    const float4* src = (const float4*)(emb + (size_t)r * EDIM);
    float v[5][8];
    float mx = 0.f;
    #pragma unroll
    for (int i = 0; i < 5; ++i) {
        int j = part + i * 8;               // 8-float group index 0..39
        #pragma unroll
        for (int t = 0; t < 8; ++t) v[i][t] = 0.f;
        if (j < 37) {
            float4 a = src[2 * j];
            float4 c = src[2 * j + 1];
            v[i][0] = a.x; v[i][1] = a.y; v[i][2] = a.z; v[i][3] = a.w;
            v[i][4] = c.x; v[i][5] = c.y; v[i][6] = c.z; v[i][7] = c.w;
        } else if (j == 37) {               // floats 296..299 valid, 300..303 pad
            float4 a = src[74];
            v[i][0] = a.x; v[i][1] = a.y; v[i][2] = a.z; v[i][3] = a.w;
        }                                   // j = 38,39: all pad zeros
        #pragma unroll
        for (int t = 0; t < 8; ++t) mx = fmaxf(mx, fabsf(v[i][t]));
    }
    mx = fmaxf(mx, __shfl_xor(mx, 1));
    mx = fmaxf(mx, __shfl_xor(mx, 2));
    mx = fmaxf(mx, __shfl_xor(mx, 4));
    float s = (mx > 0.f) ? (64.f / mx) : 0.f;   // max -> 64: e4m3 sweet spot

    float ss = 0.f;
    uint2* dst = (uint2*)(ebf + (size_t)r * ROWB);   // 40 x uint2 per row
    #pragma unroll
    for (int i = 0; i < 5; ++i) {
        int j = part + i * 8;
        unsigned int w0 = 0u, w1 = 0u;
        w0 = __builtin_amdgcn_cvt_pk_fp8_f32(v[i][0] * s, v[i][1] * s, w0, false);
        w0 = __builtin_amdgcn_cvt_pk_fp8_f32(v[i][2] * s, v[i][3] * s, w0, true);
        w1 = __builtin_amdgcn_cvt_pk_fp8_f32(v[i][4] * s, v[i][5] * s, w1, false);
        w1 = __builtin_amdgcn_cvt_pk_fp8_f32(v[i][6] * s, v[i][7] * s, w1, true);
        float g;
        g = __builtin_amdgcn_cvt_f32_fp8(w0, 0); ss += g * g;
        g = __builtin_amdgcn_cvt_f32_fp8(w0, 1); ss += g * g;
        g = __builtin_amdgcn_cvt_f32_fp8(w0, 2); ss += g * g;
        g = __builtin_amdgcn_cvt_f32_fp8(w0, 3); ss += g * g;
        g = __builtin_amdgcn_cvt_f32_fp8(w1, 0); ss += g * g;
        g = __builtin_amdgcn_cvt_f32_fp8(w1, 1); ss += g * g;
        g = __builtin_amdgcn_cvt_f32_fp8(w1, 2); ss += g * g;
        g = __builtin_amdgcn_cvt_f32_fp8(w1, 3); ss += g * g;
        uint2 o; o.x = w0; o.y = w1;
        dst[j] = o;
    }
    ss += __shfl_xor(ss, 1);
    ss += __shfl_xor(ss, 2);
    ss += __shfl_xor(ss, 4);
    if (part == 0) rnorm[r] = 1.f / (sqrtf(ss) + 1e-13f);
}

// ---------------- Phase 2: fused gather + fp8 MFMA + Gaussians + epilogue ----------------
__device__ __forceinline__ void load_frags(long* bf, const unsigned char* __restrict__ ebf,
                                           int tok, int quad)
{
    const long* src = (const long*)(ebf + (size_t)tok * ROWB);   // 40 longs/row
    #pragma unroll
    for (int ks = 0; ks < 10; ++ks)
        bf[ks] = src[quad + ks * 4];
}

__global__ __launch_bounds__(512, 2)
void knrm_main8(const int* __restrict__ qtok, const int* __restrict__ dtok,
                const unsigned char* __restrict__ ebf, const float* __restrict__ rnorm,
                const float* __restrict__ mu, const float* __restrict__ sigma,
                const float* __restrict__ dw, const float* __restrict__ db,
                float* __restrict__ out)
{
    __shared__ __align__(16) unsigned char q_buf[BQ * QSTR];   // 10752 B
    __shared__ float pkq_s[BQ * NK];
    __shared__ float rqs[BQ];
    __shared__ float red[BQ];

    const int tid  = threadIdx.x;
    const int lane = tid & 63;
    const int wv   = tid >> 6;            // 0..7
    const int b    = blockIdx.x;          // one block per batch
    const int l16  = lane & 15;
    const int quad = lane >> 4;

    for (int i = tid; i < BQ * NK; i += 512) pkq_s[i] = 0.f;
    if (tid < BQ) rqs[tid] = rnorm[qtok[b * BQ + tid]];

    // this wave's d rows: step s -> row s*128 + wv*16 + l16
    const int dbase = b * BD + wv * 16 + l16;
    int   td[4];
    float rd[4], dm[4];
    #pragma unroll
    for (int s = 0; s < 4; ++s) {
        td[s] = dtok[dbase + s * 128];
        rd[s] = rnorm[td[s]];
        dm[s] = (td[s] > 0) ? 1.f : 0.f;
    }

    // stage the 32 q rows once per batch: 16 threads/row, uint4 chunks (20/row)
    {
        int row = tid >> 4, part = tid & 15;
        int tok = qtok[b * BQ + row];
        const uint4* src  = (const uint4*)(ebf + (size_t)tok * ROWB);
        uint4*       qrow = (uint4*)&q_buf[row * QSTR];
        for (int c = part; c < 20; c += 16) qrow[c] = src[c];
    }

    // prefetch step-0 B-fragments while the barrier drains
    long bf0[10], bf1[10];
    load_frags(bf0, ebf, td[0], quad);

    __syncthreads();

    float mur[NK], cfr[NK];
    #pragma unroll
    for (int k = 0; k < NK; ++k) {
        float s = sbc(sigma[k]);
        mur[k] = sbc(mu[k]);
        cfr[k] = -0.5f / (s * s);
    }
    float rqv[8];
    #pragma unroll
    for (int slab = 0; slab < 2; ++slab)
        #pragma unroll
        for (int r = 0; r < 4; ++r)
            rqv[slab * 4 + r] = rqs[slab * 16 + quad * 4 + r];

    const unsigned char* a0 = &q_buf[l16 * QSTR + quad * 8];
    const unsigned char* a1 = a0 + 16 * QSTR;

    float pk[2][4][NK];
    #pragma unroll
    for (int slab = 0; slab < 2; ++slab)
        #pragma unroll
        for (int r = 0; r < 4; ++r)
            #pragma unroll
            for (int k = 0; k < NK; ++k) pk[slab][r][k] = 0.f;

    #pragma unroll
    for (int s = 0; s < 4; ++s) {
        const long* bf = (s & 1) ? bf1 : bf0;

        floatx4 acc0 = {0.f, 0.f, 0.f, 0.f};
        floatx4 acc1 = {0.f, 0.f, 0.f, 0.f};
        #pragma unroll
        for (int ks = 0; ks < 10; ++ks) {
            long aA = *(const long*)(a0 + ks * 32);
            long aB = *(const long*)(a1 + ks * 32);
            acc0 = __builtin_amdgcn_mfma_f32_16x16x32_fp8_fp8(aA, bf[ks], acc0, 0, 0, 0);
            acc1 = __builtin_amdgcn_mfma_f32_16x16x32_fp8_fp8(aB, bf[ks], acc1, 0, 0, 0);
        }

        // issue next step's loads BEFORE the exp tail (they land under it)
        if (s < 3) load_frags((s & 1) ? bf0 : bf1, ebf, td[s + 1], quad);

        #pragma unroll
        for (int slab = 0; slab < 2; ++slab) {
            floatx4 acc = slab ? acc1 : acc0;
            #pragma unroll
            for (int r = 0; r < 4; ++r) {
                float c0 = acc[r] * rqv[slab * 4 + r] * rd[s];
                #pragma unroll
                for (int k = 0; k < NK; ++k) {
                    float d0 = c0 - mur[k];
                    pk[slab][r][k] += dm[s] * __expf(cfr[k] * d0 * d0);
                }
            }
        }
    }

    // ONE cross-lane reduce (sum 16 d-lanes per quad) + LDS combine
    #pragma unroll
    for (int slab = 0; slab < 2; ++slab)
        #pragma unroll
        for (int r = 0; r < 4; ++r)
            #pragma unroll
            for (int k = 0; k < NK; ++k) {
                float v = pk[slab][r][k];
                v += __shfl_xor(v, 1);
                v += __shfl_xor(v, 2);
                v += __shfl_xor(v, 4);
                v += __shfl_xor(v, 8);
                if (l16 == 0)
                    atomicAdd(&pkq_s[(slab * 16 + quad * 4 + r) * NK + k], v);
            }
    __syncthreads();

    // fused epilogue: log/mask/dot -> out[b]
    if (tid < BQ) {
        int tok = qtok[b * BQ + tid];
        float sq = 0.f;
        if (tok > 0) {
            #pragma unroll
            for (int k = 0; k < NK; ++k) {
                float s = fmaxf(pkq_s[tid * NK + k], 1e-10f);
                sq += __logf(s) * 0.01f * dw[k];
            }
        }
        red[tid] = sq;
    }
    __syncthreads();
    if (tid == 0) {
        float s = db[0];
        #pragma unroll 8
        for (int i = 0; i < BQ; ++i) s += red[i];
        out[b] = s;
    }
}

extern "C" void kernel_launch(void* const* d_in, const int* in_sizes, int n_in,
                              void* d_out, int out_size, void* d_ws, size_t ws_size,
                              hipStream_t stream)
{
    const int*   qtok  = (const int*)d_in[0];
    const int*   dtok  = (const int*)d_in[1];
    const float* emb   = (const float*)d_in[2];
    const float* dw    = (const float*)d_in[3];
    const float* dbias = (const float*)d_in[4];
    const float* mu    = (const float*)d_in[5];
    const float* sg    = (const float*)d_in[6];
    float* out = (float*)d_out;

    const int V = in_sizes[2] / EDIM;   // 100000
    const size_t ebf_bytes = (size_t)V * ROWB;       // 32 MB
    const size_t rn_bytes  = (size_t)((V * 4 + 255) & ~255);

    unsigned char* ebf   = (unsigned char*)d_ws;
    float*         rnorm = (float*)((char*)d_ws + ebf_bytes);
    unsigned char* flags = (unsigned char*)((char*)d_ws + ebf_bytes + rn_bytes);

    hipMemsetAsync(flags, 0, V, stream);
    const int ntok = B * BQ + B * BD;   // 139264
    knrm_mark<<<(ntok + 255) / 256, 256, 0, stream>>>(qtok, dtok, flags);
    knrm_norm<<<(V + 31) / 32, 256, 0, stream>>>(emb, flags, ebf, rnorm, V);
    knrm_main8<<<B, 512, 0, stream>>>(qtok, dtok, ebf, rnorm, mu, sg, dw, dbias, out);
}